// Round 1
// baseline (123.832 us; speedup 1.0000x reference)
//
#include <hip/hip_runtime.h>

// Problem constants (from reference): B=16384, S=336, F=8, H=1
constexpr int S_ = 336;
constexpr int F_ = 8;
constexpr int U_ = 8;   // unroll / prefetch depth (336 = 42*8)

struct CellW { float4 wx, wh, b; };

__device__ __forceinline__ float fast_sigmoid(float x) {
    // 1/(1+exp(-x)); v_exp_f32 + v_rcp_f32 via HIP fast intrinsics
    return __fdividef(1.0f, 1.0f + __expf(-x));
}

__device__ __forceinline__ float fast_tanh(float x) {
    // tanh(x) = 2/(1+exp(-2x)) - 1
    return fmaf(2.0f, __fdividef(1.0f, 1.0f + __expf(-2.0f * x)), -1.0f);
}

__device__ __forceinline__ void lstm_cell(float xt, float& h, float& c, const CellW& w) {
    // gate order per jnp.split: i, f, g, o
    float zi = fmaf(xt, w.wx.x, fmaf(h, w.wh.x, w.b.x));
    float zf = fmaf(xt, w.wx.y, fmaf(h, w.wh.y, w.b.y));
    float zg = fmaf(xt, w.wx.z, fmaf(h, w.wh.z, w.b.z));
    float zo = fmaf(xt, w.wx.w, fmaf(h, w.wh.w, w.b.w));
    float i = fast_sigmoid(zi);
    float f = fast_sigmoid(zf);
    float g = fast_tanh(zg);
    float o = fast_sigmoid(zo);
    c = fmaf(f, c, i * g);
    h = o * fast_tanh(c);
}

__global__ __launch_bounds__(64) void lstm_fused_kernel(
    const float* __restrict__ x,
    const float* __restrict__ Wx1, const float* __restrict__ Wh1, const float* __restrict__ b1,
    const float* __restrict__ Wx2, const float* __restrict__ Wh2, const float* __restrict__ b2,
    const float* __restrict__ fcW, const float* __restrict__ fcb,
    float* __restrict__ out, int B)
{
    int b = blockIdx.x * blockDim.x + threadIdx.x;
    if (b >= B) return;

    CellW w1 { *reinterpret_cast<const float4*>(Wx1),
               *reinterpret_cast<const float4*>(Wh1),
               *reinterpret_cast<const float4*>(b1) };
    CellW w2 { *reinterpret_cast<const float4*>(Wx2),
               *reinterpret_cast<const float4*>(Wh2),
               *reinterpret_cast<const float4*>(b2) };
    float fw = fcW[0];
    float fb = fcb[0];

    const float* xp = x + (size_t)b * (S_ * F_) + (F_ - 1);  // feature 7 of each step
    float* op = out + (size_t)b * S_;

    float h1 = 0.f, c1 = 0.f, h2 = 0.f, c2 = 0.f;

    float cur[U_], nxt[U_];
    #pragma unroll
    for (int u = 0; u < U_; ++u) cur[u] = xp[u * F_];

    constexpr int NG = S_ / U_;  // 42 groups
    #pragma unroll 1
    for (int g = 0; g < NG - 1; ++g) {
        // prefetch next group's x values (independent of the recurrence chain)
        const float* xn = xp + (size_t)(g + 1) * (U_ * F_);
        #pragma unroll
        for (int u = 0; u < U_; ++u) nxt[u] = xn[u * F_];

        float r[U_];
        #pragma unroll
        for (int u = 0; u < U_; ++u) {
            lstm_cell(cur[u], h1, c1, w1);
            lstm_cell(h1,     h2, c2, w2);
            r[u] = fmaf(h2, fw, fb);
        }
        float4* o4 = reinterpret_cast<float4*>(op + g * U_);
        o4[0] = make_float4(r[0], r[1], r[2], r[3]);
        o4[1] = make_float4(r[4], r[5], r[6], r[7]);

        #pragma unroll
        for (int u = 0; u < U_; ++u) cur[u] = nxt[u];
    }
    // final group (no prefetch)
    {
        float r[U_];
        #pragma unroll
        for (int u = 0; u < U_; ++u) {
            lstm_cell(cur[u], h1, c1, w1);
            lstm_cell(h1,     h2, c2, w2);
            r[u] = fmaf(h2, fw, fb);
        }
        float4* o4 = reinterpret_cast<float4*>(op + (NG - 1) * U_);
        o4[0] = make_float4(r[0], r[1], r[2], r[3]);
        o4[1] = make_float4(r[4], r[5], r[6], r[7]);
    }
}

extern "C" void kernel_launch(void* const* d_in, const int* in_sizes, int n_in,
                              void* d_out, int out_size, void* d_ws, size_t ws_size,
                              hipStream_t stream) {
    const float* x   = (const float*)d_in[0];
    const float* Wx1 = (const float*)d_in[1];
    const float* Wh1 = (const float*)d_in[2];
    const float* b1  = (const float*)d_in[3];
    const float* Wx2 = (const float*)d_in[4];
    const float* Wh2 = (const float*)d_in[5];
    const float* b2  = (const float*)d_in[6];
    const float* fcW = (const float*)d_in[7];
    const float* fcb = (const float*)d_in[8];
    float* out = (float*)d_out;

    int B = in_sizes[0] / (S_ * F_);   // 16384
    dim3 block(64);
    dim3 grid((B + 63) / 64);          // 256 blocks -> 1 wave per CU
    lstm_fused_kernel<<<grid, block, 0, stream>>>(
        x, Wx1, Wh1, b1, Wx2, Wh2, b2, fcW, fcb, out, B);
}

// Round 2
// 50.361 us; speedup vs baseline: 2.4589x; 2.4589x over previous
//
#include <hip/hip_runtime.h>

// B=16384, S=336, F=8, H=1. 8 lanes per sequence:
//   lane&3 = gate (i,f,g,o), lane&4 = layer (0: LSTM1, 1: LSTM2, lagged 1 step)
constexpr int S_ = 336;
constexpr float L2E = 1.4426950408889634f;  // log2(e)

template<int CTRL>
__device__ __forceinline__ float dpp_f(float old_, float src) {
    return __int_as_float(__builtin_amdgcn_update_dpp(
        __float_as_int(old_), __float_as_int(src), CTRL, 0xF, 0xF, false));
}
__device__ __forceinline__ float exp2_hw(float x){ float r; asm("v_exp_f32 %0, %1" : "=v"(r) : "v"(x)); return r; }
__device__ __forceinline__ float rcp_hw (float x){ float r; asm("v_rcp_f32 %0, %1" : "=v"(r) : "v"(x)); return r; }

struct P { float wx, wh, bb, m2B, fw, fb; bool is_l1; };

// One pipelined step: lanes 0-3 run cell1 on xt, lanes 4-7 run cell2 on h1(prev)
// delivered via row_shr:4. All lanes uniform instruction stream.
// act = A + B*tanh(s*z) with z' = 2*s*log2e*z folded into weights:
//   sigmoid: A=B=0.5, s=0.5  -> act = 1 - rcp(1+exp2(z'))
//   tanh:    A=0,B=1, s=1    -> act = 1 - 2*rcp(1+exp2(z'))
__device__ __forceinline__ float lstm_step(float xt, float& h, float& c, const P& p) {
    float hsh = dpp_f<0x114>(h, h);          // row_shr:4 — lanes 4..7 read lanes 0..3 (h1 prev)
    float in  = p.is_l1 ? xt : hsh;
    float z   = fmaf(in, p.wx, fmaf(h, p.wh, p.bb));
    float r   = rcp_hw(1.0f + exp2_hw(z));
    float a   = fmaf(p.m2B, r, 1.0f);
    float i_  = dpp_f<0x00>(a, a);           // quad_perm bcast lane0 (i)
    float f_  = dpp_f<0x55>(a, a);           // bcast lane1 (f)
    float g_  = dpp_f<0xAA>(a, a);           // bcast lane2 (g)
    float o_  = dpp_f<0xFF>(a, a);           // bcast lane3 (o)
    c = fmaf(f_, c, i_ * g_);
    float r2  = rcp_hw(1.0f + exp2_hw(c * (2.0f * L2E)));
    h = fmaf(-2.0f * o_, r2, o_);            // h = o * tanh(c)
    return fmaf(h, p.fw, p.fb);              // FC output (valid in lanes 4-7)
}

__global__ __launch_bounds__(512) void lstm_lane8_kernel(
    const float* __restrict__ x,
    const float* __restrict__ Wx1, const float* __restrict__ Wh1, const float* __restrict__ b1,
    const float* __restrict__ Wx2, const float* __restrict__ Wh2, const float* __restrict__ b2,
    const float* __restrict__ fcW, const float* __restrict__ fcb,
    float* __restrict__ out)
{
    int tid  = blockIdx.x * 512 + threadIdx.x;
    int seq  = tid >> 3;
    int l8   = tid & 7;
    int gate = l8 & 3;
    bool is_l1 = (l8 < 4);

    float sc = (gate == 2) ? 2.0f * L2E : L2E;
    const float* Wx = is_l1 ? Wx1 : Wx2;
    const float* Wh = is_l1 ? Wh1 : Wh2;
    const float* Bb = is_l1 ? b1  : b2;
    P p;
    p.wx = Wx[gate] * sc; p.wh = Wh[gate] * sc; p.bb = Bb[gate] * sc;
    p.m2B = (gate == 2) ? -2.0f : -1.0f;
    p.is_l1 = is_l1;
    p.fw = fcW[0]; p.fb = fcb[0];

    const float* xp = x + (size_t)seq * (S_ * 8) + 7;   // feature 7 per step
    float* op = out + (size_t)seq * S_;
    bool store_lane = (l8 == 4);

    float h = 0.f, c = 0.f;

    // iteration 0: cell1 consumes x_0; cell2 (lanes 4-7) computes garbage -> reset it
    lstm_step(xp[0], h, c, p);
    h = is_l1 ? h : 0.f;
    c = is_l1 ? c : 0.f;

    float cur[8], nxt[8];
    #pragma unroll
    for (int u = 0; u < 8; ++u) cur[u] = xp[8 * (1 + u)];   // iters 1..8

    // iterations k = 8g+1 .. 8g+8 produce out indices 8g .. 8g+7
    #pragma unroll 1
    for (int g = 0; g < 40; ++g) {
        const float* xn = xp + 8 * (8 * g + 9);             // prefetch iters for group g+1
        #pragma unroll
        for (int u = 0; u < 8; ++u) nxt[u] = xn[8 * u];

        float r[8];
        #pragma unroll
        for (int u = 0; u < 8; ++u) r[u] = lstm_step(cur[u], h, c, p);

        if (store_lane) {
            *(float4*)(op + 8 * g)     = make_float4(r[0], r[1], r[2], r[3]);
            *(float4*)(op + 8 * g + 4) = make_float4(r[4], r[5], r[6], r[7]);
        }
        #pragma unroll
        for (int u = 0; u < 8; ++u) cur[u] = nxt[u];
    }

    // g = 40: iters 321..328 (out 320..327); prefetch iters 329..335 + drain slot
    {
        const float* xn = xp + 8 * 329;
        #pragma unroll
        for (int u = 0; u < 7; ++u) nxt[u] = xn[8 * u];
        nxt[7] = 0.f;                                       // iter 336 = drain (no x)

        float r[8];
        #pragma unroll
        for (int u = 0; u < 8; ++u) r[u] = lstm_step(cur[u], h, c, p);
        if (store_lane) {
            *(float4*)(op + 320) = make_float4(r[0], r[1], r[2], r[3]);
            *(float4*)(op + 324) = make_float4(r[4], r[5], r[6], r[7]);
        }
        #pragma unroll
        for (int u = 0; u < 8; ++u) cur[u] = nxt[u];
    }

    // g = 41: iters 329..336 (out 328..335); iter 336 only drains cell2
    {
        float r[8];
        #pragma unroll
        for (int u = 0; u < 8; ++u) r[u] = lstm_step(cur[u], h, c, p);
        if (store_lane) {
            *(float4*)(op + 328) = make_float4(r[0], r[1], r[2], r[3]);
            *(float4*)(op + 332) = make_float4(r[4], r[5], r[6], r[7]);
        }
    }
}

extern "C" void kernel_launch(void* const* d_in, const int* in_sizes, int n_in,
                              void* d_out, int out_size, void* d_ws, size_t ws_size,
                              hipStream_t stream) {
    const float* x   = (const float*)d_in[0];
    const float* Wx1 = (const float*)d_in[1];
    const float* Wh1 = (const float*)d_in[2];
    const float* b1  = (const float*)d_in[3];
    const float* Wx2 = (const float*)d_in[4];
    const float* Wh2 = (const float*)d_in[5];
    const float* b2  = (const float*)d_in[6];
    const float* fcW = (const float*)d_in[7];
    const float* fcb = (const float*)d_in[8];
    float* out = (float*)d_out;

    int B = in_sizes[0] / (S_ * 8);          // 16384
    int threads = B * 8;                     // 131072 = 8 waves/CU = 2 per SIMD
    lstm_lane8_kernel<<<threads / 512, 512, 0, stream>>>(
        x, Wx1, Wh1, b1, Wx2, Wh2, b2, fcW, fcb, out);
}

// Round 3
// 44.276 us; speedup vs baseline: 2.7968x; 1.1374x over previous
//
#include <hip/hip_runtime.h>

// B=16384, S=336, F=8, H=1. 8 lanes per sequence:
//   lane&3 = gate (i,f,g,o), lane&4 = layer (0: LSTM1, 1: LSTM2, lagged 1 step)
constexpr int S_ = 336;
constexpr float L2E = 1.4426950408889634f;   // log2(e)
constexpr float K2  = 2.0f * L2E;

template<int CTRL>
__device__ __forceinline__ float dpp_f(float old_, float src) {
    return __int_as_float(__builtin_amdgcn_update_dpp(
        __float_as_int(old_), __float_as_int(src), CTRL, 0xF, 0xF, false));
}
__device__ __forceinline__ float exp2_hw(float x){ float r; asm("v_exp_f32 %0, %1" : "=v"(r) : "v"(x)); return r; }
__device__ __forceinline__ float rcp_hw (float x){ float r; asm("v_rcp_f32 %0, %1" : "=v"(r) : "v"(x)); return r; }

struct P { float wx, wh, bb, Ag, Bg, fw, fb; bool is_l1; };

// State cs = 2*log2(e)*c (pre-scaled so tanh(c) = 1 - 2*rcp(1+exp2(cs)) needs no mul).
// Gate i's broadcast value is pre-scaled by K2 so cs-update stays consistent:
//   cs' = f*cs + (K2*i)*g
// All gate activations: act = Ag + Bg*rcp(1+exp2(z')) with z' = s*log2e*z folded
// into the weights (s=1 for sigmoid gates, s=2 for the g-gate tanh).
__device__ __forceinline__ float lstm_step(float xt, float& h, float& cs, const P& p) {
    float hsh = dpp_f<0x114>(h, h);          // row_shr:4 — lanes 4..7 read h1(prev) from lanes 0..3
    float in  = p.is_l1 ? xt : hsh;
    float z   = fmaf(in, p.wx, fmaf(h, p.wh, p.bb));
    float r   = rcp_hw(1.0f + exp2_hw(z));
    float a   = fmaf(p.Bg, r, p.Ag);
    float i_  = dpp_f<0x00>(a, a);           // bcast lane0: K2*sigmoid(zi)
    float f_  = dpp_f<0x55>(a, a);           // bcast lane1: sigmoid(zf)
    float g_  = dpp_f<0xAA>(a, a);           // bcast lane2: tanh(zg)
    float o_  = dpp_f<0xFF>(a, a);           // bcast lane3: sigmoid(zo)
    cs = fmaf(f_, cs, i_ * g_);
    float r2  = rcp_hw(1.0f + exp2_hw(cs));
    h = fmaf(-2.0f * o_, r2, o_);            // h = o * tanh(c)
    return fmaf(h, p.fw, p.fb);              // FC output (valid in lanes 4-7)
}

__global__ __launch_bounds__(512) void lstm_lane8_kernel(
    const float* __restrict__ x,
    const float* __restrict__ Wx1, const float* __restrict__ Wh1, const float* __restrict__ b1,
    const float* __restrict__ Wx2, const float* __restrict__ Wh2, const float* __restrict__ b2,
    const float* __restrict__ fcW, const float* __restrict__ fcb,
    float* __restrict__ out)
{
    int tid  = blockIdx.x * 512 + threadIdx.x;
    int seq  = tid >> 3;
    int l8   = tid & 7;
    int gate = l8 & 3;
    bool is_l1 = (l8 < 4);

    float sc = (gate == 2) ? K2 : L2E;
    const float* Wx = is_l1 ? Wx1 : Wx2;
    const float* Wh = is_l1 ? Wh1 : Wh2;
    const float* Bb = is_l1 ? b1  : b2;
    P p;
    p.wx = Wx[gate] * sc; p.wh = Wh[gate] * sc; p.bb = Bb[gate] * sc;
    p.Ag = (gate == 0) ? K2  : 1.0f;
    p.Bg = (gate == 0) ? -K2 : ((gate == 2) ? -2.0f : -1.0f);
    p.is_l1 = is_l1;
    p.fw = fcW[0]; p.fb = fcb[0];

    const float* xp = x + (size_t)seq * (S_ * 8) + 7;   // feature 7 of each step
    float* op = out + (size_t)seq * S_;
    bool store_lane = (l8 == 4);

    // Prefetch x0 and buffer A (iters 1..8) before any compute.
    float x0 = xp[0];
    float A[8], Bf[8];
    #pragma unroll
    for (int u = 0; u < 8; ++u) A[u] = xp[8 * (1 + u)];
    __builtin_amdgcn_sched_barrier(0);

    float h = 0.f, cs = 0.f;
    // iteration 0: cell1 consumes x_0; cell2 lanes compute garbage -> reset
    lstm_step(x0, h, cs, p);
    h  = is_l1 ? h  : 0.f;
    cs = is_l1 ? cs : 0.f;

    // Groups j=0..41, group j = iters 8j+1..8j+8 -> out 8j..8j+7.
    // Double-buffered pairs t=0..19 handle groups 2t (A) and 2t+1 (B);
    // t=20 peeled (group 41's last slot is the pipeline drain, x=0).
    #pragma unroll 1
    for (int t = 0; t < 20; ++t) {
        const float* xb = xp + 8 * (16 * t + 9);
        #pragma unroll
        for (int u = 0; u < 8; ++u) Bf[u] = xb[8 * u];     // iters 16t+9..16t+16
        __builtin_amdgcn_sched_barrier(0);

        float r[8];
        #pragma unroll
        for (int u = 0; u < 8; ++u) r[u] = lstm_step(A[u], h, cs, p);
        if (store_lane) {
            *(float4*)(op + 16 * t)     = make_float4(r[0], r[1], r[2], r[3]);
            *(float4*)(op + 16 * t + 4) = make_float4(r[4], r[5], r[6], r[7]);
        }

        const float* xa = xp + 8 * (16 * t + 17);
        #pragma unroll
        for (int u = 0; u < 8; ++u) A[u] = xa[8 * u];      // iters 16t+17..16t+24
        __builtin_amdgcn_sched_barrier(0);

        #pragma unroll
        for (int u = 0; u < 8; ++u) r[u] = lstm_step(Bf[u], h, cs, p);
        if (store_lane) {
            *(float4*)(op + 16 * t + 8)  = make_float4(r[0], r[1], r[2], r[3]);
            *(float4*)(op + 16 * t + 12) = make_float4(r[4], r[5], r[6], r[7]);
        }
    }

    // t=20: group 40 from A (iters 321..328), group 41 from B (iters 329..336)
    {
        const float* xb = xp + 8 * 329;
        #pragma unroll
        for (int u = 0; u < 7; ++u) Bf[u] = xb[8 * u];     // iters 329..335
        Bf[7] = 0.f;                                       // iter 336 = drain (no x)
        __builtin_amdgcn_sched_barrier(0);

        float r[8];
        #pragma unroll
        for (int u = 0; u < 8; ++u) r[u] = lstm_step(A[u], h, cs, p);
        if (store_lane) {
            *(float4*)(op + 320) = make_float4(r[0], r[1], r[2], r[3]);
            *(float4*)(op + 324) = make_float4(r[4], r[5], r[6], r[7]);
        }
        #pragma unroll
        for (int u = 0; u < 8; ++u) r[u] = lstm_step(Bf[u], h, cs, p);
        if (store_lane) {
            *(float4*)(op + 328) = make_float4(r[0], r[1], r[2], r[3]);
            *(float4*)(op + 332) = make_float4(r[4], r[5], r[6], r[7]);
        }
    }
}

extern "C" void kernel_launch(void* const* d_in, const int* in_sizes, int n_in,
                              void* d_out, int out_size, void* d_ws, size_t ws_size,
                              hipStream_t stream) {
    const float* x   = (const float*)d_in[0];
    const float* Wx1 = (const float*)d_in[1];
    const float* Wh1 = (const float*)d_in[2];
    const float* b1  = (const float*)d_in[3];
    const float* Wx2 = (const float*)d_in[4];
    const float* Wh2 = (const float*)d_in[5];
    const float* b2  = (const float*)d_in[6];
    const float* fcW = (const float*)d_in[7];
    const float* fcb = (const float*)d_in[8];
    float* out = (float*)d_out;

    int B = in_sizes[0] / (S_ * 8);          // 16384
    int threads = B * 8;                     // 131072 = 2048 waves = 2 per SIMD
    lstm_lane8_kernel<<<threads / 512, 512, 0, stream>>>(
        x, Wx1, Wh1, b1, Wx2, Wh2, b2, fcW, fcb, out);
}